// Round 2
// baseline (3237.231 us; speedup 1.0000x reference)
//
#include <hip/hip_runtime.h>
#include <cmath>

// LogEig -> MaxPool2d(4,2) -> ExpEig, fused, one 32x32 SPD matrix per 64-thread block.
// R4: R3 showed occupancy 31->45% with NO speedup and flat VALUBusy (61%) =>
// the saturated resource is the per-CU LDS pipe (~460 ds_*_b128/block ~= 100% of
// the LDS return bandwidth over the 183us runtime). Fix: cut DS traffic.
//   Every mm32 needs P's r-slice and Q's c-slice (both column slices, via symmetry).
//   The Q c-slice is REUSED across multiply pairs (Tc: T2 & T3; T3c: M2 & M3;
//   Tec: T2e & T3e; T3ec: R & F). Capture it into 128 VGPRs during the first
//   multiply of each pair; the second multiply streams only P (32 reads, not 64).
// DS ops/block ~460 -> ~360 (-22%). FMA count & numerics unchanged.
// LDS stays 8KB (2 buffers) = 20 blocks/CU, __launch_bounds__(64,5).

#define CENTER 4.5f
#define INVH   0.2857142857142857f

struct LogCoeffs { float b[16]; };  // power-basis coeffs in t=(x-4.5)/3.5, deg 9

// acc += P*Q, 32x32, P symmetric (P-rows read through columns). Captures Q's
// c-slice into Qc[32][4] (fully unrolled => Qc stays in VGPRs).
__device__ __forceinline__ void mm32_ldq(const float* __restrict__ P,
                                         const float* __restrict__ Q,
                                         float a[4][4], float Qc[32][4],
                                         int rq, int cq) {
#pragma unroll
  for (int j = 0; j < 32; ++j) {
    const float4 pv = *(const float4*)(P + j*32 + 4*rq);
    const float4 qv = *(const float4*)(Q + j*32 + 4*cq);
    Qc[j][0] = qv.x; Qc[j][1] = qv.y; Qc[j][2] = qv.z; Qc[j][3] = qv.w;
    const float pr[4] = {pv.x, pv.y, pv.z, pv.w};
#pragma unroll
    for (int i = 0; i < 4; ++i)
#pragma unroll
      for (int e = 0; e < 4; ++e)
        a[i][e] = fmaf(pr[i], Qc[j][e], a[i][e]);
  }
}

// acc += P*Q with Q's c-slice already in registers: streams only P (32 reads).
__device__ __forceinline__ void mm32_regq(const float* __restrict__ P,
                                          const float Qc[32][4],
                                          float a[4][4], int rq) {
#pragma unroll
  for (int j = 0; j < 32; ++j) {
    const float4 pv = *(const float4*)(P + j*32 + 4*rq);
    const float pr[4] = {pv.x, pv.y, pv.z, pv.w};
#pragma unroll
    for (int i = 0; i < 4; ++i)
#pragma unroll
      for (int e = 0; e < 4; ++e)
        a[i][e] = fmaf(pr[i], Qc[j][e], a[i][e]);
  }
}

__device__ __forceinline__ void st32(float* __restrict__ D, const float a[4][4],
                                     int rq, int cq) {
#pragma unroll
  for (int i = 0; i < 4; ++i)
    *(float4*)(D + (4*rq + i)*32 + 4*cq) = make_float4(a[i][0], a[i][1], a[i][2], a[i][3]);
}

// a = k0*I + k1*Tt + k2*T2t  (this thread's 4x4 tile; diag iff rq==cq)
__device__ __forceinline__ void initc(float a[4][4], float k0, float k1, float k2,
                                      const float Tt[4][4], const float T2t[4][4],
                                      bool diag) {
#pragma unroll
  for (int i = 0; i < 4; ++i)
#pragma unroll
    for (int e = 0; e < 4; ++e) {
      float v = fmaf(k2, T2t[i][e], k1 * Tt[i][e]);
      if (diag && i == e) v += k0;
      a[i][e] = v;
    }
}

// 16x16: a[0..3] += P[r][*] dot Q[*][4c..4c+3], capturing Q's c-slice.
__device__ __forceinline__ void mm16_ldq(const float* __restrict__ P,
                                         const float* __restrict__ Q,
                                         float a[4], float Qc[16][4],
                                         int r, int c) {
  float pr[16];
#pragma unroll
  for (int k = 0; k < 4; ++k) {
    float4 v = *(const float4*)(P + r*16 + 4*k);
    pr[4*k] = v.x; pr[4*k+1] = v.y; pr[4*k+2] = v.z; pr[4*k+3] = v.w;
  }
#pragma unroll
  for (int j = 0; j < 16; ++j) {
    float4 qv = *(const float4*)(Q + j*16 + 4*c);
    Qc[j][0] = qv.x; Qc[j][1] = qv.y; Qc[j][2] = qv.z; Qc[j][3] = qv.w;
    a[0] = fmaf(pr[j], Qc[j][0], a[0]);
    a[1] = fmaf(pr[j], Qc[j][1], a[1]);
    a[2] = fmaf(pr[j], Qc[j][2], a[2]);
    a[3] = fmaf(pr[j], Qc[j][3], a[3]);
  }
}

// 16x16 with cached Q c-slice: streams only P rows (4 reads).
__device__ __forceinline__ void mm16_regq(const float* __restrict__ P,
                                          const float Qc[16][4],
                                          float a[4], int r) {
  float pr[16];
#pragma unroll
  for (int k = 0; k < 4; ++k) {
    float4 v = *(const float4*)(P + r*16 + 4*k);
    pr[4*k] = v.x; pr[4*k+1] = v.y; pr[4*k+2] = v.z; pr[4*k+3] = v.w;
  }
#pragma unroll
  for (int j = 0; j < 16; ++j) {
    a[0] = fmaf(pr[j], Qc[j][0], a[0]);
    a[1] = fmaf(pr[j], Qc[j][1], a[1]);
    a[2] = fmaf(pr[j], Qc[j][2], a[2]);
    a[3] = fmaf(pr[j], Qc[j][3], a[3]);
  }
}

// plain 16x16 (both operands from LDS) for the squarings
__device__ __forceinline__ void mm16(const float* __restrict__ P,
                                     const float* __restrict__ Q,
                                     float a[4], int r, int c) {
  float pr[16];
#pragma unroll
  for (int k = 0; k < 4; ++k) {
    float4 v = *(const float4*)(P + r*16 + 4*k);
    pr[4*k] = v.x; pr[4*k+1] = v.y; pr[4*k+2] = v.z; pr[4*k+3] = v.w;
  }
#pragma unroll
  for (int j = 0; j < 16; ++j) {
    float4 qv = *(const float4*)(Q + j*16 + 4*c);
    a[0] = fmaf(pr[j], qv.x, a[0]);
    a[1] = fmaf(pr[j], qv.y, a[1]);
    a[2] = fmaf(pr[j], qv.z, a[2]);
    a[3] = fmaf(pr[j], qv.w, a[3]);
  }
}

__global__ __launch_bounds__(64, 5)
void logeig_pool_expeig(const float* __restrict__ x, float* __restrict__ out,
                        LogCoeffs lc) {
  __shared__ __align__(16) float S[2048];         // 8 KB -> 20 blocks/CU
  float* A  = S;                                  // T -> T3 -> logX -> exp buffers
  float* Bv = S + 1024;                           // T2 -> M1 -> M2 -> rowmax RM[32][16]

  const int m = blockIdx.x;
  const int t = threadIdx.x;
  const int rq = t >> 3, cq = t & 7;
  const float* xg = x + (size_t)m * 1024;

  // ---- load + map to T = (X - 4.5 I)/3.5 ----
#pragma unroll
  for (int i = 0; i < 4; ++i) {
    int fi = (i*64 + t) * 4;
    float4 v = *(const float4*)(xg + fi);
    int row = fi >> 5, cb = fi & 31, dpos = row - cb;
    float* vp = (float*)&v;
#pragma unroll
    for (int e = 0; e < 4; ++e) {
      float val = vp[e];
      if (e == dpos) val -= CENTER;
      vp[e] = val * INVH;
    }
    *(float4*)(A + fi) = v;
  }
  __syncthreads();

  // own T tile -> regs
  float Tt[4][4];
#pragma unroll
  for (int i = 0; i < 4; ++i) {
    float4 v = *(const float4*)(A + (4*rq + i)*32 + 4*cq);
    Tt[i][0] = v.x; Tt[i][1] = v.y; Tt[i][2] = v.z; Tt[i][3] = v.w;
  }

  float acc[4][4];
  float Qc[32][4];                                // cached Q c-slice (128 VGPR)
  const bool dg = (rq == cq);

  // T2 = T*T -> Bv, capturing Tc = T[j][4cq..]
#pragma unroll
  for (int i = 0; i < 4; ++i)
#pragma unroll
    for (int e = 0; e < 4; ++e) acc[i][e] = 0.0f;
  mm32_ldq(A, A, acc, Qc, rq, cq);
  float T2t[4][4];
#pragma unroll
  for (int i = 0; i < 4; ++i)
#pragma unroll
    for (int e = 0; e < 4; ++e) T2t[i][e] = acc[i][e];
  st32(Bv, acc, rq, cq);
  __syncthreads();

  // T3 = T2*T -> overwrite A (T dead in LDS: Tt in regs, Tc cached).
  // Streams only T2 rows (32 reads). Single-wave block => DS program order
  // guarantees the store can't pass this block's own reads.
#pragma unroll
  for (int i = 0; i < 4; ++i)
#pragma unroll
    for (int e = 0; e < 4; ++e) acc[i][e] = 0.0f;
  mm32_regq(Bv, Qc, acc, rq);
  st32(A, acc, rq, cq);
  __syncthreads();

  // M1 = b9*T3 + b8*T2 + b7*T + b6*I  (T3 tile is in acc; all reg-resident)
  // -> overwrite Bv (T2 dead in LDS)
  {
    float m1[4][4];
    initc(m1, lc.b[6], lc.b[7], lc.b[8], Tt, T2t, dg);
#pragma unroll
    for (int i = 0; i < 4; ++i)
#pragma unroll
      for (int e = 0; e < 4; ++e) m1[i][e] = fmaf(lc.b[9], acc[i][e], m1[i][e]);
    st32(Bv, m1, rq, cq);
  }
  __syncthreads();

  // M2 = M1*T3 + (b3 I + b4 T + b5 T2) -> overwrite Bv; captures T3c.
  initc(acc, lc.b[3], lc.b[4], lc.b[5], Tt, T2t, dg);
  mm32_ldq(Bv, A, acc, Qc, rq, cq);
  st32(Bv, acc, rq, cq);
  __syncthreads();

  // M3 = M2*T3 + (b0 I + b1 T + b2 T2) = log(X) -> overwrite A (T3 dead:
  // its c-slice is cached). Streams only M2 rows.
  initc(acc, lc.b[0], lc.b[1], lc.b[2], Tt, T2t, dg);
  mm32_regq(Bv, Qc, acc, rq);
  st32(A, acc, rq, cq);
  __syncthreads();

  // ---- separable MaxPool 4x4 stride 2: rowmax4 then colmax4 ----
  // rowmax RM[32][16] -> Bv (M2 dead)
  {
    const int half = t >> 5, l = t & 31;
    const float* rp = A + l*32 + 16*half;
    float4 w0 = *(const float4*)(rp + 0);
    float4 w1 = *(const float4*)(rp + 4);
    float4 w2 = *(const float4*)(rp + 8);
    float4 w3 = *(const float4*)(rp + 12);
    float2 e2 = *(const float2*)(A + l*32 + 16);  // cols 16,17 (used by half 0 only)
    float v[16] = {w0.x,w0.y,w0.z,w0.w, w1.x,w1.y,w1.z,w1.w,
                   w2.x,w2.y,w2.z,w2.w, w3.x,w3.y,w3.z,w3.w};
    float rm[8];
#pragma unroll
    for (int j = 0; j < 7; ++j)
      rm[j] = fmaxf(fmaxf(v[2*j], v[2*j+1]), fmaxf(v[2*j+2], v[2*j+3]));
    rm[7] = (half == 0) ? fmaxf(fmaxf(v[14], v[15]), fmaxf(e2.x, e2.y)) : 0.0f;
    *(float4*)(Bv + l*16 + 8*half + 0) = make_float4(rm[0], rm[1], rm[2], rm[3]);
    *(float4*)(Bv + l*16 + 8*half + 4) = make_float4(rm[4], rm[5], rm[6], rm[7]);
  }
  __syncthreads();

  // stage 2: P16[i][j] = max over 4 rows of RM; tile stays in regs
  const int r16 = t >> 2, c16 = t & 3;
  float p16[4];
  if (r16 < 15) {
    float4 m0 = *(const float4*)(Bv + (2*r16 + 0)*16 + 4*c16);
    float4 m1 = *(const float4*)(Bv + (2*r16 + 1)*16 + 4*c16);
    float4 m2 = *(const float4*)(Bv + (2*r16 + 2)*16 + 4*c16);
    float4 m3 = *(const float4*)(Bv + (2*r16 + 3)*16 + 4*c16);
    p16[0] = fmaxf(fmaxf(m0.x, m1.x), fmaxf(m2.x, m3.x));
    p16[1] = fmaxf(fmaxf(m0.y, m1.y), fmaxf(m2.y, m3.y));
    p16[2] = fmaxf(fmaxf(m0.z, m1.z), fmaxf(m2.z, m3.z));
    p16[3] = fmaxf(fmaxf(m0.w, m1.w), fmaxf(m2.w, m3.w));
    if (c16 == 3) p16[3] = 0.0f;                 // col-15 pad
  } else {
    p16[0] = p16[1] = p16[2] = p16[3] = 0.0f;    // row-15 pad
  }

  // ---- inf-norm via shuffles -> scaling ----
  float s = fabsf(p16[0]) + fabsf(p16[1]) + fabsf(p16[2]) + fabsf(p16[3]);
  s += __shfl_xor(s, 1);
  s += __shfl_xor(s, 2);                          // row sums
  s = fmaxf(s, __shfl_xor(s, 4));
  s = fmaxf(s, __shfl_xor(s, 8));
  s = fmaxf(s, __shfl_xor(s, 16));
  s = fmaxf(s, __shfl_xor(s, 32));                // global max
  int e2i; (void)frexpf(s, &e2i);
  const int sc = e2i > 0 ? e2i : 0;               // theta in [0.5,1)
  const float scale = ldexpf(1.0f, -sc);

  // exp buffers in A (logX dead after pooling stage 1):
  // Te@0, T2e@256, T3e@512, M@768 (16x16 each, stride 16)
  float* Te  = A;
  float* T2e = A + 256;
  float* T3e = A + 512;
  float* Me  = A + 768;

  float Tet[4] = {p16[0]*scale, p16[1]*scale, p16[2]*scale, p16[3]*scale};
  *(float4*)(Te + r16*16 + 4*c16) = make_float4(Tet[0], Tet[1], Tet[2], Tet[3]);
  __syncthreads();

  // exp deg-8 PS: grouped as (C2*Q3 + C1)*Q3 + C0
  const float C0_ = 1.0f, C1_ = 1.0f, C2_ = 0.5f;
  const float C3_ = 1.6666667e-1f, C4_ = 4.1666668e-2f, C5_ = 8.3333338e-3f;
  const float C6_ = 1.3888889e-3f, C7_ = 1.9841270e-4f, C8_ = 2.4801588e-5f;

  float a4[4];
  float Qc16[16][4];                              // cached 16x16 Q c-slice
  // T2e = Te*Te, capturing Tec
  a4[0] = a4[1] = a4[2] = a4[3] = 0.0f;
  mm16_ldq(Te, Te, a4, Qc16, r16, c16);
  float T2et[4] = {a4[0], a4[1], a4[2], a4[3]};
  *(float4*)(T2e + r16*16 + 4*c16) = make_float4(a4[0], a4[1], a4[2], a4[3]);
  __syncthreads();
  // T3e = T2e*Te: streams T2e rows only, Tec cached
  a4[0] = a4[1] = a4[2] = a4[3] = 0.0f;
  mm16_regq(T2e, Qc16, a4, r16);
  *(float4*)(T3e + r16*16 + 4*c16) = make_float4(a4[0], a4[1], a4[2], a4[3]);
  __syncthreads();
  // M = c6 I + c7 Te + c8 T2e (tiles in regs)
#pragma unroll
  for (int e = 0; e < 4; ++e) {
    float v = fmaf(C8_, T2et[e], C7_ * Tet[e]);
    if (4*c16 + e == r16) v += C6_;
    a4[e] = v;
  }
  *(float4*)(Me + r16*16 + 4*c16) = make_float4(a4[0], a4[1], a4[2], a4[3]);
  __syncthreads();
  // R = M*T3e + (c3 I + c4 Te + c5 T2e) -> T2e slot; captures T3ec
#pragma unroll
  for (int e = 0; e < 4; ++e) {
    float v = fmaf(C5_, T2et[e], C4_ * Tet[e]);
    if (4*c16 + e == r16) v += C3_;
    a4[e] = v;
  }
  mm16_ldq(Me, T3e, a4, Qc16, r16, c16);
  *(float4*)(T2e + r16*16 + 4*c16) = make_float4(a4[0], a4[1], a4[2], a4[3]);
  __syncthreads();
  // F = R*T3e + (c0 I + c1 Te + c2 T2e) -> Te slot; T3ec cached
#pragma unroll
  for (int e = 0; e < 4; ++e) {
    float v = fmaf(C2_, T2et[e], C1_ * Tet[e]);
    if (4*c16 + e == r16) v += C0_;
    a4[e] = v;
  }
  mm16_regq(T2e, Qc16, a4, r16);
  *(float4*)(Te + r16*16 + 4*c16) = make_float4(a4[0], a4[1], a4[2], a4[3]);
  __syncthreads();

  // squarings: ping-pong A+0 <-> A+512
  int cur = 0, oth = 512;
  for (int it = 0; it < sc; ++it) {
    a4[0] = a4[1] = a4[2] = a4[3] = 0.0f;
    mm16(A + cur, A + cur, a4, r16, c16);
    *(float4*)(A + oth + r16*16 + 4*c16) = make_float4(a4[0], a4[1], a4[2], a4[3]);
    __syncthreads();
    int tmp = cur; cur = oth; oth = tmp;
  }

  // ---- write 15x15 ----
  const float* cu = A + cur;
  float* og = out + (size_t)m * 225;
#pragma unroll
  for (int w2 = 0; w2 < 4; ++w2) {
    int q = t + 64*w2;
    if (q < 225) {
      int i = q / 15, j = q % 15;
      og[q] = cu[i*16 + j];
    }
  }
}

extern "C" void kernel_launch(void* const* d_in, const int* in_sizes, int n_in,
                              void* d_out, int out_size, void* d_ws, size_t ws_size,
                              hipStream_t stream) {
  (void)n_in; (void)d_ws; (void)ws_size; (void)out_size;
  const float* x = (const float*)d_in[0];
  float* out = (float*)d_out;
  const int nmat = in_sizes[0] >> 10;

  // deg-9 Chebyshev coeffs of log on [1,8] -> power basis (host, fp64)
  LogCoeffs lc;
  {
    const double lo = 1.0, hi = 8.0;
    const double c = 0.5*(lo + hi), h = 0.5*(hi - lo), w = h / c;
    const double z = (std::sqrt(1.0 - w*w) - 1.0) / w;
    const int DEG = 9;
    double a[16] = {0};
    a[0] = std::log(c) - std::log(1.0 + z*z);
    double zk = 1.0;
    for (int k = 1; k <= DEG; ++k) { zk *= z; a[k] = -2.0 * zk / k; }
    double b[16], Tp[16], Tc[16], Tn[16];
    for (int j = 0; j < 16; ++j) { b[j] = 0; Tp[j] = 0; Tc[j] = 0; }
    Tp[0] = 1.0; Tc[1] = 1.0;
    b[0] += a[0] * Tp[0];
    for (int j = 0; j < 16; ++j) b[j] += a[1] * Tc[j];
    for (int k = 2; k <= DEG; ++k) {
      for (int j = 0; j < 16; ++j) {
        double v = -Tp[j];
        if (j > 0) v += 2.0 * Tc[j-1];
        Tn[j] = v;
      }
      for (int j = 0; j < 16; ++j) b[j] += a[k] * Tn[j];
      for (int j = 0; j < 16; ++j) { Tp[j] = Tc[j]; Tc[j] = Tn[j]; }
    }
    for (int j = 0; j < 16; ++j) lc.b[j] = (float)b[j];
  }

  logeig_pool_expeig<<<dim3(nmat), dim3(64), 0, stream>>>(x, out, lc);
}

// Round 3
// 303.583 us; speedup vs baseline: 10.6634x; 10.6634x over previous
//
#include <hip/hip_runtime.h>
#include <cmath>

// LogEig -> MaxPool2d(4,2) -> ExpEig, fused, one 32x32 SPD matrix per 64-thread block.
// R5: R4's Q-register-cache went to SCRATCH (WRITE_SIZE 30MB->6.3GB) because
// __launch_bounds__(64,5) caps VGPR at ~102 and the cache needs 128. Fixes:
//  - __launch_bounds__(64,2): VGPR cap 256. Occupancy falls to ~8 blocks/CU,
//    which R3 proved harmless (occupancy 31->45% gave zero speedup; the LDS
//    pipe is the limiter).
//  - Q-cache as NAMED float4 Q0..Q31 via macros (no aggregate for SROA to miss).
//  - Bank-conflict pads (the 7.5M SQ_LDS_BANK_CONFLICT): 32x32 buffers stride
//    32->36 (st32 was 8-way: bank dep only on cq; now 4-way, reads stay
//    broadcast-clean), 16x16 exp buffers stride 16->20 (mm16 P-row reads were
//    8-way: 16 addrs -> 2 bank quads; now 2-way = free).
// DS instr count ~ -17% (Q c-slice reused across multiply pairs: Tc serves
// T2&T3, T3c serves M2&M3, Tec serves T2e&T3e, T3ec serves R&F), conflict
// cycles ~ -4x. FMA order unchanged => bit-identical numerics.

#define CENTER 4.5f
#define INVH   0.2857142857142857f
#define LDA 36   // 32x32 buffer row stride (floats)
#define LDE 20   // 16x16 exp buffer row stride (floats)

struct LogCoeffs { float b[16]; };  // power-basis coeffs in t=(x-4.5)/3.5, deg 9

#define REP16(M) M(0) M(1) M(2) M(3) M(4) M(5) M(6) M(7) \
                 M(8) M(9) M(10) M(11) M(12) M(13) M(14) M(15)
#define REP32(M) REP16(M) M(16) M(17) M(18) M(19) M(20) M(21) M(22) M(23) \
                 M(24) M(25) M(26) M(27) M(28) M(29) M(30) M(31)

#define DECLQ(j) float4 Q##j;

// 16 FMAs of one rank-1 step: acc[i][e] += pv[i]*qv[e]
#define ACC16(pv, qv) \
  acc[0][0]=fmaf(pv.x,qv.x,acc[0][0]); acc[0][1]=fmaf(pv.x,qv.y,acc[0][1]); \
  acc[0][2]=fmaf(pv.x,qv.z,acc[0][2]); acc[0][3]=fmaf(pv.x,qv.w,acc[0][3]); \
  acc[1][0]=fmaf(pv.y,qv.x,acc[1][0]); acc[1][1]=fmaf(pv.y,qv.y,acc[1][1]); \
  acc[1][2]=fmaf(pv.y,qv.z,acc[1][2]); acc[1][3]=fmaf(pv.y,qv.w,acc[1][3]); \
  acc[2][0]=fmaf(pv.z,qv.x,acc[2][0]); acc[2][1]=fmaf(pv.z,qv.y,acc[2][1]); \
  acc[2][2]=fmaf(pv.z,qv.z,acc[2][2]); acc[2][3]=fmaf(pv.z,qv.w,acc[2][3]); \
  acc[3][0]=fmaf(pv.w,qv.x,acc[3][0]); acc[3][1]=fmaf(pv.w,qv.y,acc[3][1]); \
  acc[3][2]=fmaf(pv.w,qv.z,acc[3][2]); acc[3][3]=fmaf(pv.w,qv.w,acc[3][3]);

// 32x32 rank-1 step, loading Q c-slice into named reg Q<j> (P symmetric:
// P "rows" read through columns)
#define MM32LD(j) { const float4 pv = *(const float4*)(Pm + (j)*LDA + 4*rq); \
  Q##j = *(const float4*)(Qm + (j)*LDA + 4*cq); ACC16(pv, Q##j) }
// 32x32 rank-1 step with Q c-slice already in regs: streams only P
#define MM32RQ(j) { const float4 pv = *(const float4*)(Pm + (j)*LDA + 4*rq); \
  ACC16(pv, Q##j) }

// 16x16 steps (stride LDE), P row in pr[16]
#define MM16LD(j) { Q##j = *(const float4*)(Qm + (j)*LDE + 4*c16); \
  a4[0]=fmaf(pr[j],Q##j.x,a4[0]); a4[1]=fmaf(pr[j],Q##j.y,a4[1]); \
  a4[2]=fmaf(pr[j],Q##j.z,a4[2]); a4[3]=fmaf(pr[j],Q##j.w,a4[3]); }
#define MM16RQ(j) { \
  a4[0]=fmaf(pr[j],Q##j.x,a4[0]); a4[1]=fmaf(pr[j],Q##j.y,a4[1]); \
  a4[2]=fmaf(pr[j],Q##j.z,a4[2]); a4[3]=fmaf(pr[j],Q##j.w,a4[3]); }

#define LDPR(Pm) { \
  float4 v0 = *(const float4*)((Pm) + r16*LDE + 0); \
  float4 v1 = *(const float4*)((Pm) + r16*LDE + 4); \
  float4 v2 = *(const float4*)((Pm) + r16*LDE + 8); \
  float4 v3 = *(const float4*)((Pm) + r16*LDE + 12); \
  pr[0]=v0.x; pr[1]=v0.y; pr[2]=v0.z; pr[3]=v0.w; \
  pr[4]=v1.x; pr[5]=v1.y; pr[6]=v1.z; pr[7]=v1.w; \
  pr[8]=v2.x; pr[9]=v2.y; pr[10]=v2.z; pr[11]=v2.w; \
  pr[12]=v3.x; pr[13]=v3.y; pr[14]=v3.z; pr[15]=v3.w; }

__device__ __forceinline__ void st36(float* __restrict__ D, const float a[4][4],
                                     int rq, int cq) {
#pragma unroll
  for (int i = 0; i < 4; ++i)
    *(float4*)(D + (4*rq + i)*LDA + 4*cq) = make_float4(a[i][0], a[i][1], a[i][2], a[i][3]);
}

// a = k0*I + k1*Tt + k2*T2t  (this thread's 4x4 tile; diag iff rq==cq)
__device__ __forceinline__ void initc(float a[4][4], float k0, float k1, float k2,
                                      const float Tt[4][4], const float T2t[4][4],
                                      bool diag) {
#pragma unroll
  for (int i = 0; i < 4; ++i)
#pragma unroll
    for (int e = 0; e < 4; ++e) {
      float v = fmaf(k2, T2t[i][e], k1 * Tt[i][e]);
      if (diag && i == e) v += k0;
      a[i][e] = v;
    }
}

// plain 16x16 (both operands from LDS, stride LDE) for the squarings
__device__ __forceinline__ void mm16s(const float* __restrict__ P,
                                      const float* __restrict__ Q,
                                      float a[4], int r, int c) {
  float pr[16];
#pragma unroll
  for (int k = 0; k < 4; ++k) {
    float4 v = *(const float4*)(P + r*LDE + 4*k);
    pr[4*k] = v.x; pr[4*k+1] = v.y; pr[4*k+2] = v.z; pr[4*k+3] = v.w;
  }
#pragma unroll
  for (int j = 0; j < 16; ++j) {
    float4 qv = *(const float4*)(Q + j*LDE + 4*c);
    a[0] = fmaf(pr[j], qv.x, a[0]);
    a[1] = fmaf(pr[j], qv.y, a[1]);
    a[2] = fmaf(pr[j], qv.z, a[2]);
    a[3] = fmaf(pr[j], qv.w, a[3]);
  }
}

__global__ __launch_bounds__(64, 2)
void logeig_pool_expeig(const float* __restrict__ x, float* __restrict__ out,
                        LogCoeffs lc) {
  __shared__ __align__(16) float S[2304];         // 2 x 32x36 = 9216 B
  float* A  = S;                                  // T -> T3 -> logX -> exp buffers
  float* Bv = S + 1152;                           // T2 -> M1 -> M2 -> rowmax RM[32][16] -> Me

  const int m = blockIdx.x;
  const int t = threadIdx.x;
  const int rq = t >> 3, cq = t & 7;
  const float* xg = x + (size_t)m * 1024;

  REP32(DECLQ)                                    // named Q c-slice cache (128 VGPR)

  // ---- load + map to T = (X - 4.5 I)/3.5 ----
#pragma unroll
  for (int i = 0; i < 4; ++i) {
    int fi = (i*64 + t) * 4;
    float4 v = *(const float4*)(xg + fi);
    int row = fi >> 5, cb = fi & 31, dpos = row - cb;
    float* vp = (float*)&v;
#pragma unroll
    for (int e = 0; e < 4; ++e) {
      float val = vp[e];
      if (e == dpos) val -= CENTER;
      vp[e] = val * INVH;
    }
    *(float4*)(A + row*LDA + cb) = v;
  }
  __syncthreads();

  // own T tile -> regs
  float Tt[4][4];
#pragma unroll
  for (int i = 0; i < 4; ++i) {
    float4 v = *(const float4*)(A + (4*rq + i)*LDA + 4*cq);
    Tt[i][0] = v.x; Tt[i][1] = v.y; Tt[i][2] = v.z; Tt[i][3] = v.w;
  }

  float acc[4][4];
  const bool dg = (rq == cq);

  // T2 = T*T -> Bv, capturing Tc = T[j][4cq..] into Q0..Q31
#pragma unroll
  for (int i = 0; i < 4; ++i)
#pragma unroll
    for (int e = 0; e < 4; ++e) acc[i][e] = 0.0f;
  { const float* Pm = A; const float* Qm = A; REP32(MM32LD) }
  float T2t[4][4];
#pragma unroll
  for (int i = 0; i < 4; ++i)
#pragma unroll
    for (int e = 0; e < 4; ++e) T2t[i][e] = acc[i][e];
  st36(Bv, acc, rq, cq);
  __syncthreads();

  // T3 = T2*T -> overwrite A (T dead in LDS: Tt in regs, Tc in Q regs).
  // Streams only T2 rows. Single-wave block => DS program order protects
  // the overwrite.
#pragma unroll
  for (int i = 0; i < 4; ++i)
#pragma unroll
    for (int e = 0; e < 4; ++e) acc[i][e] = 0.0f;
  { const float* Pm = Bv; REP32(MM32RQ) }
  st36(A, acc, rq, cq);
  __syncthreads();

  // M1 = b9*T3 + b8*T2 + b7*T + b6*I  (T3 tile is in acc) -> overwrite Bv
  {
    float m1[4][4];
    initc(m1, lc.b[6], lc.b[7], lc.b[8], Tt, T2t, dg);
#pragma unroll
    for (int i = 0; i < 4; ++i)
#pragma unroll
      for (int e = 0; e < 4; ++e) m1[i][e] = fmaf(lc.b[9], acc[i][e], m1[i][e]);
    st36(Bv, m1, rq, cq);
  }
  __syncthreads();

  // M2 = M1*T3 + (b3 I + b4 T + b5 T2) -> overwrite Bv; captures T3 c-slice.
  initc(acc, lc.b[3], lc.b[4], lc.b[5], Tt, T2t, dg);
  { const float* Pm = Bv; const float* Qm = A; REP32(MM32LD) }
  st36(Bv, acc, rq, cq);
  __syncthreads();

  // M3 = M2*T3 + (b0 I + b1 T + b2 T2) = log(X) -> overwrite A (T3c in regs).
  initc(acc, lc.b[0], lc.b[1], lc.b[2], Tt, T2t, dg);
  { const float* Pm = Bv; REP32(MM32RQ) }
  st36(A, acc, rq, cq);
  __syncthreads();

  // ---- separable MaxPool 4x4 stride 2: rowmax4 then colmax4 ----
  // rowmax RM[32][16] -> Bv (M2 dead)
  {
    const int half = t >> 5, l = t & 31;
    const float* rp = A + l*LDA + 16*half;
    float4 w0 = *(const float4*)(rp + 0);
    float4 w1 = *(const float4*)(rp + 4);
    float4 w2 = *(const float4*)(rp + 8);
    float4 w3 = *(const float4*)(rp + 12);
    float2 e2 = *(const float2*)(A + l*LDA + 16);  // cols 16,17 (half 0 only)
    float v[16] = {w0.x,w0.y,w0.z,w0.w, w1.x,w1.y,w1.z,w1.w,
                   w2.x,w2.y,w2.z,w2.w, w3.x,w3.y,w3.z,w3.w};
    float rm[8];
#pragma unroll
    for (int j = 0; j < 7; ++j)
      rm[j] = fmaxf(fmaxf(v[2*j], v[2*j+1]), fmaxf(v[2*j+2], v[2*j+3]));
    rm[7] = (half == 0) ? fmaxf(fmaxf(v[14], v[15]), fmaxf(e2.x, e2.y)) : 0.0f;
    *(float4*)(Bv + l*16 + 8*half + 0) = make_float4(rm[0], rm[1], rm[2], rm[3]);
    *(float4*)(Bv + l*16 + 8*half + 4) = make_float4(rm[4], rm[5], rm[6], rm[7]);
  }
  __syncthreads();

  // stage 2: P16[i][j] = max over 4 rows of RM; tile stays in regs
  const int r16 = t >> 2, c16 = t & 3;
  float p16[4];
  if (r16 < 15) {
    float4 m0 = *(const float4*)(Bv + (2*r16 + 0)*16 + 4*c16);
    float4 m1 = *(const float4*)(Bv + (2*r16 + 1)*16 + 4*c16);
    float4 m2 = *(const float4*)(Bv + (2*r16 + 2)*16 + 4*c16);
    float4 m3 = *(const float4*)(Bv + (2*r16 + 3)*16 + 4*c16);
    p16[0] = fmaxf(fmaxf(m0.x, m1.x), fmaxf(m2.x, m3.x));
    p16[1] = fmaxf(fmaxf(m0.y, m1.y), fmaxf(m2.y, m3.y));
    p16[2] = fmaxf(fmaxf(m0.z, m1.z), fmaxf(m2.z, m3.z));
    p16[3] = fmaxf(fmaxf(m0.w, m1.w), fmaxf(m2.w, m3.w));
    if (c16 == 3) p16[3] = 0.0f;                 // col-15 pad
  } else {
    p16[0] = p16[1] = p16[2] = p16[3] = 0.0f;    // row-15 pad
  }

  // ---- inf-norm via shuffles -> scaling ----
  float s = fabsf(p16[0]) + fabsf(p16[1]) + fabsf(p16[2]) + fabsf(p16[3]);
  s += __shfl_xor(s, 1);
  s += __shfl_xor(s, 2);                          // row sums
  s = fmaxf(s, __shfl_xor(s, 4));
  s = fmaxf(s, __shfl_xor(s, 8));
  s = fmaxf(s, __shfl_xor(s, 16));
  s = fmaxf(s, __shfl_xor(s, 32));                // global max
  int e2i; (void)frexpf(s, &e2i);
  const int sc = e2i > 0 ? e2i : 0;               // theta in [0.5,1)
  const float scale = ldexpf(1.0f, -sc);

  // exp buffers (stride LDE=20, 320 floats each): Te@A, T2e@A+320, T3e@A+640,
  // Me@Bv (RM dead after stage 2)
  float* Te  = A;
  float* T2e = A + 320;
  float* T3e = A + 640;
  float* Me  = Bv;

  float Tet[4] = {p16[0]*scale, p16[1]*scale, p16[2]*scale, p16[3]*scale};
  *(float4*)(Te + r16*LDE + 4*c16) = make_float4(Tet[0], Tet[1], Tet[2], Tet[3]);
  __syncthreads();

  // exp deg-8 PS: grouped as (C2*Q3 + C1)*Q3 + C0
  const float C0_ = 1.0f, C1_ = 1.0f, C2_ = 0.5f;
  const float C3_ = 1.6666667e-1f, C4_ = 4.1666668e-2f, C5_ = 8.3333338e-3f;
  const float C6_ = 1.3888889e-3f, C7_ = 1.9841270e-4f, C8_ = 2.4801588e-5f;

  float a4[4];
  float pr[16];
  // T2e = Te*Te, capturing Tec into Q0..Q15
  a4[0] = a4[1] = a4[2] = a4[3] = 0.0f;
  LDPR(Te)
  { const float* Qm = Te; REP16(MM16LD) }
  float T2et[4] = {a4[0], a4[1], a4[2], a4[3]};
  *(float4*)(T2e + r16*LDE + 4*c16) = make_float4(a4[0], a4[1], a4[2], a4[3]);
  __syncthreads();
  // T3e = T2e*Te: streams T2e rows only, Tec cached
  a4[0] = a4[1] = a4[2] = a4[3] = 0.0f;
  LDPR(T2e)
  REP16(MM16RQ)
  *(float4*)(T3e + r16*LDE + 4*c16) = make_float4(a4[0], a4[1], a4[2], a4[3]);
  __syncthreads();
  // M = c6 I + c7 Te + c8 T2e (tiles in regs) -> Me
#pragma unroll
  for (int e = 0; e < 4; ++e) {
    float v = fmaf(C8_, T2et[e], C7_ * Tet[e]);
    if (4*c16 + e == r16) v += C6_;
    a4[e] = v;
  }
  *(float4*)(Me + r16*LDE + 4*c16) = make_float4(a4[0], a4[1], a4[2], a4[3]);
  __syncthreads();
  // R = M*T3e + (c3 I + c4 Te + c5 T2e) -> T2e slot; captures T3ec
#pragma unroll
  for (int e = 0; e < 4; ++e) {
    float v = fmaf(C5_, T2et[e], C4_ * Tet[e]);
    if (4*c16 + e == r16) v += C3_;
    a4[e] = v;
  }
  LDPR(Me)
  { const float* Qm = T3e; REP16(MM16LD) }
  *(float4*)(T2e + r16*LDE + 4*c16) = make_float4(a4[0], a4[1], a4[2], a4[3]);
  __syncthreads();
  // F = R*T3e + (c0 I + c1 Te + c2 T2e) -> Te slot; T3ec cached
#pragma unroll
  for (int e = 0; e < 4; ++e) {
    float v = fmaf(C2_, T2et[e], C1_ * Tet[e]);
    if (4*c16 + e == r16) v += C0_;
    a4[e] = v;
  }
  LDPR(T2e)
  REP16(MM16RQ)
  *(float4*)(Te + r16*LDE + 4*c16) = make_float4(a4[0], a4[1], a4[2], a4[3]);
  __syncthreads();

  // squarings: ping-pong A+0 <-> A+640
  float* pc = A;
  float* po = A + 640;
  for (int it = 0; it < sc; ++it) {
    a4[0] = a4[1] = a4[2] = a4[3] = 0.0f;
    mm16s(pc, pc, a4, r16, c16);
    *(float4*)(po + r16*LDE + 4*c16) = make_float4(a4[0], a4[1], a4[2], a4[3]);
    __syncthreads();
    float* tmp = pc; pc = po; po = tmp;
  }

  // ---- write 15x15 ----
  float* og = out + (size_t)m * 225;
#pragma unroll
  for (int w2 = 0; w2 < 4; ++w2) {
    int q = t + 64*w2;
    if (q < 225) {
      int i = q / 15, j = q % 15;
      og[q] = pc[i*LDE + j];
    }
  }
}

extern "C" void kernel_launch(void* const* d_in, const int* in_sizes, int n_in,
                              void* d_out, int out_size, void* d_ws, size_t ws_size,
                              hipStream_t stream) {
  (void)n_in; (void)d_ws; (void)ws_size; (void)out_size;
  const float* x = (const float*)d_in[0];
  float* out = (float*)d_out;
  const int nmat = in_sizes[0] >> 10;

  // deg-9 Chebyshev coeffs of log on [1,8] -> power basis (host, fp64)
  LogCoeffs lc;
  {
    const double lo = 1.0, hi = 8.0;
    const double c = 0.5*(lo + hi), h = 0.5*(hi - lo), w = h / c;
    const double z = (std::sqrt(1.0 - w*w) - 1.0) / w;
    const int DEG = 9;
    double a[16] = {0};
    a[0] = std::log(c) - std::log(1.0 + z*z);
    double zk = 1.0;
    for (int k = 1; k <= DEG; ++k) { zk *= z; a[k] = -2.0 * zk / k; }
    double b[16], Tp[16], Tc[16], Tn[16];
    for (int j = 0; j < 16; ++j) { b[j] = 0; Tp[j] = 0; Tc[j] = 0; }
    Tp[0] = 1.0; Tc[1] = 1.0;
    b[0] += a[0] * Tp[0];
    for (int j = 0; j < 16; ++j) b[j] += a[1] * Tc[j];
    for (int k = 2; k <= DEG; ++k) {
      for (int j = 0; j < 16; ++j) {
        double v = -Tp[j];
        if (j > 0) v += 2.0 * Tc[j-1];
        Tn[j] = v;
      }
      for (int j = 0; j < 16; ++j) b[j] += a[k] * Tn[j];
      for (int j = 0; j < 16; ++j) { Tp[j] = Tc[j]; Tc[j] = Tn[j]; }
    }
    for (int j = 0; j < 16; ++j) lc.b[j] = (float)b[j];
  }

  logeig_pool_expeig<<<dim3(nmat), dim3(64), 0, stream>>>(x, out, lc);
}